// Round 11
// baseline (292.136 us; speedup 1.0000x reference)
//
#include <hip/hip_runtime.h>
#include <math.h>

typedef __attribute__((ext_vector_type(4))) float f32x4;
typedef __attribute__((ext_vector_type(8))) short bf16x8;

// Problem constants
#define NB 16
#define NT 2048
#define NMEL 80
#define NPOS 512          // stacked positions per batch
#define EDIM 16
#define NEMB 8192
#define ENCD 512
#define MROWS (NB*511)    // 8176 logit rows
#define MPAD 8192
#define NVT 64            // 8192 / 128 col tiles

__device__ __forceinline__ unsigned short f2bf(float x) {
    union { float f; unsigned u; } v; v.f = x;
    unsigned r = v.u + 0x7fffu + ((v.u >> 16) & 1u);
    return (unsigned short)(r >> 16);
}

__device__ __forceinline__ void gl_lds16(const void* gsrc, void* lds) {
    __builtin_amdgcn_global_load_lds(
        (const __attribute__((address_space(1))) unsigned int*)gsrc,
        (__attribute__((address_space(3))) unsigned int*)lds,
        16, 0, 0);
}

// ---------------- Kernel 1: prep = codes (blocks 0..511, global-direct scan)
//                  + enc->bf16 (512..1023) + tno->bf16 transpose (1024..2047).
__global__ __launch_bounds__(256) void prep_kernel(
    const float* __restrict__ feats, const float* __restrict__ proj,
    const float* __restrict__ emb, const float* __restrict__ enc,
    const float* __restrict__ tno,
    int* __restrict__ codes, int* __restrict__ presence,
    unsigned short* __restrict__ encB, unsigned short* __restrict__ tnoT)
{
    __shared__ float tileT[32][33];         // tno transpose staging
    const int bid = blockIdx.x;
    const int tid = threadIdx.x;

    if (bid < 512) {
        // ---- codes path: per-lane global emb scan (no LDS, no syncs) ----
        const int lane = tid & 63;
        const int wave = tid >> 6;
        const int gbase = bid * 16 + wave * 4;
        if (bid < 32) presence[bid * 256 + tid] = 0;

        float yn[4][EDIM];
        #pragma unroll
        for (int pi = 0; pi < 4; ++pi) {
            const int g = gbase + pi;
            const int b = g >> 9;
            const int i = g & 511;
            float xv[5];
            float s = 0.f, sq = 0.f;
            #pragma unroll
            for (int qq = 0; qq < 5; ++qq) {
                const int d = lane + 64 * qq;
                const int j = d / 80, k = d - j * 80;
                const float v = feats[((b * NT) + (i * 4 + j)) * NMEL + k];
                xv[qq] = v; s += v; sq += v * v;
            }
            for (int m = 1; m < 64; m <<= 1) { s += __shfl_xor(s, m); sq += __shfl_xor(sq, m); }
            const float mean = s * (1.0f / 320.0f);
            const float var  = sq * (1.0f / 320.0f) - mean * mean;
            const float rstd = rsqrtf(var + 1e-6f);
            float acc[EDIM];
            #pragma unroll
            for (int e = 0; e < EDIM; ++e) acc[e] = 0.f;
            #pragma unroll
            for (int qq = 0; qq < 5; ++qq) {
                const int d = lane + 64 * qq;
                const float xn = (xv[qq] - mean) * rstd;
                #pragma unroll
                for (int e = 0; e < EDIM; ++e) acc[e] += xn * proj[d * EDIM + e];
            }
            for (int m = 1; m < 64; m <<= 1) {
                #pragma unroll
                for (int e = 0; e < EDIM; ++e) acc[e] += __shfl_xor(acc[e], m);
            }
            float nsq = 0.f;
            #pragma unroll
            for (int e = 0; e < EDIM; ++e) nsq += acc[e] * acc[e];
            const float inv = 1.0f / (sqrtf(nsq) + 1e-8f);
            #pragma unroll
            for (int e = 0; e < EDIM; ++e) yn[pi][e] = acc[e] * inv;
        }

        // per-lane scan: lane owns embeddings {i*64 + lane}, ascending index
        float mind[4]; int mini[4];
        #pragma unroll
        for (int pi = 0; pi < 4; ++pi) { mind[pi] = INFINITY; mini[pi] = 0x7fffffff; }

        #pragma unroll 2
        for (int i = 0; i < 128; ++i) {
            const int v = i * 64 + lane;
            const float* ep = &emb[(size_t)v * EDIM];
            const float4 e0 = *(const float4*)&ep[0];
            const float4 e1 = *(const float4*)&ep[4];
            const float4 e2v = *(const float4*)&ep[8];
            const float4 e3 = *(const float4*)&ep[12];
            const float e2 = e0.x*e0.x + e0.y*e0.y + e0.z*e0.z + e0.w*e0.w
                           + e1.x*e1.x + e1.y*e1.y + e1.z*e1.z + e1.w*e1.w
                           + e2v.x*e2v.x + e2v.y*e2v.y + e2v.z*e2v.z + e2v.w*e2v.w
                           + e3.x*e3.x + e3.y*e3.y + e3.z*e3.z + e3.w*e3.w;
            const float h2 = 0.5f * e2;
            #pragma unroll
            for (int pi = 0; pi < 4; ++pi) {
                const float dot = yn[pi][0]*e0.x + yn[pi][1]*e0.y + yn[pi][2]*e0.z + yn[pi][3]*e0.w
                                + yn[pi][4]*e1.x + yn[pi][5]*e1.y + yn[pi][6]*e1.z + yn[pi][7]*e1.w
                                + yn[pi][8]*e2v.x + yn[pi][9]*e2v.y + yn[pi][10]*e2v.z + yn[pi][11]*e2v.w
                                + yn[pi][12]*e3.x + yn[pi][13]*e3.y + yn[pi][14]*e3.z + yn[pi][15]*e3.w;
                const float sc = h2 - dot;
                if (sc < mind[pi]) { mind[pi] = sc; mini[pi] = v; }
            }
        }
        for (int m = 1; m < 64; m <<= 1) {
            #pragma unroll
            for (int pi = 0; pi < 4; ++pi) {
                const float ov = __shfl_xor(mind[pi], m);
                const int   oi = __shfl_xor(mini[pi], m);
                if (ov < mind[pi] || (ov == mind[pi] && oi < mini[pi])) { mind[pi] = ov; mini[pi] = oi; }
            }
        }
        if (lane == 0) {
            #pragma unroll
            for (int pi = 0; pi < 4; ++pi) codes[gbase + pi] = mini[pi];
        }
    } else if (bid < 1024) {
        // ---- enc f32 -> encB bf16 [8192][512], padded rows zero ----
        const int bid2 = bid - 512;          // 0..511 -> 16 rows each
        #pragma unroll
        for (int pass = 0; pass < 4; ++pass) {
            const int m = bid2 * 16 + pass * 4 + (tid >> 6);
            const int d = (tid & 63) * 8;
            bf16x8 o;
            if (m < MROWS) {
                const int b = m / 511, t = m - b * 511;
                const float4 f0 = *(const float4*)&enc[((size_t)(b * 512 + t)) * ENCD + d];
                const float4 f1 = *(const float4*)&enc[((size_t)(b * 512 + t)) * ENCD + d + 4];
                o[0] = f2bf(f0.x); o[1] = f2bf(f0.y); o[2] = f2bf(f0.z); o[3] = f2bf(f0.w);
                o[4] = f2bf(f1.x); o[5] = f2bf(f1.y); o[6] = f2bf(f1.z); o[7] = f2bf(f1.w);
            } else {
                o = (bf16x8){0,0,0,0,0,0,0,0};
            }
            *(bf16x8*)&encB[(size_t)m * ENCD + d] = o;
        }
    } else {
        // ---- tno f32 [512][8192] -> tnoT bf16 [8192][512] ----
        const int bid2 = bid - 1024;         // 0..1023 -> 4 tiles each
        const int tx = tid & 31, ty = tid >> 5;   // 32 x 8
        #pragma unroll
        for (int it = 0; it < 4; ++it) {
            const int tile = bid2 * 4 + it;       // 0..4095
            const int n0 = (tile & 255) * 32;
            const int k0 = (tile >> 8) * 32;
            __syncthreads();
            #pragma unroll
            for (int i = 0; i < 4; ++i)
                tileT[ty + 8 * i][tx] = tno[(size_t)(k0 + ty + 8 * i) * NEMB + n0 + tx];
            __syncthreads();
            #pragma unroll
            for (int i = 0; i < 4; ++i)
                tnoT[(size_t)(n0 + ty + 8 * i) * ENCD + k0 + tx] = f2bf(tileT[tx][ty + 8 * i]);
        }
    }
}

// ---------------- Kernel 2: bf16 MFMA GEMM, BK=64, double-buffered, 1 barrier/step ----
// r4 template with BK doubled: 8 K-steps x 128 MFMA/block; stage(t+1) issued right
// after the opening barrier, vmcnt(0) drained at step end (full compute phase of cover).
__global__ __launch_bounds__(256, 2) void logits_mfma(
    const unsigned short* __restrict__ encB, const unsigned short* __restrict__ tnoT,
    const int* __restrict__ codes,
    float* __restrict__ pm, float* __restrict__ ps, int* __restrict__ pidx,
    float* __restrict__ tgtlog)
{
    __shared__ __align__(16) unsigned short As2[2][128 * 64];   // 32 KB
    __shared__ __align__(16) unsigned short Bs2[2][128 * 64];   // 32 KB
    __shared__ float redM[2][128];
    __shared__ float redS[2][128];
    __shared__ int   redI[2][128];

    const int tid  = threadIdx.x;
    const int lane = tid & 63;
    const int wave = tid >> 6;
    const int wr = wave >> 1, wc = wave & 1;

    // XCD-aware mapping, mt-fastest within each XCD chunk
    const int bid = blockIdx.x;
    const int xcd = bid & 7;
    const int idx = bid >> 3;
    const int mt  = xcd * 8 + (idx & 7);
    const int vt  = idx >> 3;
    const int m0 = mt * 128, n0 = vt * 128;

    // staging: rows of 64 bf16 (128B = 8 chunks of 16B); one gl_lds = 8 rows (1KB).
    // involution: LDS slot s of row r holds global chunk s ^ (r&7); relative row = lane>>3.
    const int r8  = lane >> 3;                               // 0..7
    const int gcs = ((lane & 7) ^ (lane >> 3)) * 8;          // pre-swizzled source chunk (elems)
    const size_t abase = (size_t)(m0 + wave * 32 + r8) * ENCD + gcs;
    const size_t bbase = (size_t)(n0 + wave * 32 + r8) * ENCD + gcs;

#define STAGE(t, buf)                                                                    \
    {                                                                                    \
        const int k0s = (t) * 64;                                                        \
        _Pragma("unroll")                                                                \
        for (int i = 0; i < 4; ++i) {                                                    \
            gl_lds16(encB + abase + (size_t)i * 8 * ENCD + k0s,                          \
                     &As2[buf][(wave * 32 + i * 8) * 64]);                               \
            gl_lds16(tnoT + bbase + (size_t)i * 8 * ENCD + k0s,                          \
                     &Bs2[buf][(wave * 32 + i * 8) * 64]);                               \
        }                                                                                \
    }

    f32x4 acc[4][4];
    #pragma unroll
    for (int i = 0; i < 4; ++i)
        #pragma unroll
        for (int j = 0; j < 4; ++j)
            acc[i][j] = (f32x4){0.f, 0.f, 0.f, 0.f};

    const int l15 = lane & 15, q = lane >> 4;

    STAGE(0, 0);
    asm volatile("s_waitcnt vmcnt(0)" ::: "memory");
    __builtin_amdgcn_s_barrier();

    #pragma unroll
    for (int t = 0; t < 8; ++t) {
        __builtin_amdgcn_sched_barrier(0);
        if (t + 1 < 8) STAGE(t + 1, (t + 1) & 1);
        const unsigned short* Ab = As2[t & 1];
        const unsigned short* Bb = Bs2[t & 1];
        #pragma unroll
        for (int ks = 0; ks < 2; ++ks) {
            const int ca = (((ks * 4 + q) ^ (l15 & 7)) * 8);   // swizzled chunk (elems)
            bf16x8 a[4], b[4];
            #pragma unroll
            for (int mi = 0; mi < 4; ++mi)
                a[mi] = *(const bf16x8*)&Ab[(wr * 64 + mi * 16 + l15) * 64 + ca];
            #pragma unroll
            for (int ni = 0; ni < 4; ++ni)
                b[ni] = *(const bf16x8*)&Bb[(wc * 64 + ni * 16 + l15) * 64 + ca];
            __builtin_amdgcn_s_setprio(1);
            #pragma unroll
            for (int mi = 0; mi < 4; ++mi)
                #pragma unroll
                for (int ni = 0; ni < 4; ++ni)
                    acc[mi][ni] = __builtin_amdgcn_mfma_f32_16x16x32_bf16(a[mi], b[ni], acc[mi][ni], 0, 0, 0);
            __builtin_amdgcn_s_setprio(0);
        }
        asm volatile("s_waitcnt vmcnt(0)" ::: "memory");
        __builtin_amdgcn_s_barrier();
    }
#undef STAGE

    // Epilogue: per-row partial max / first-argmax / sumexp over this block's 128 cols.
    #pragma unroll
    for (int mi = 0; mi < 4; ++mi) {
        #pragma unroll
        for (int r = 0; r < 4; ++r) {
            const int rl = wr * 64 + mi * 16 + q * 4 + r;   // local row 0..127
            float lm = -INFINITY; int li = 0;
            #pragma unroll
            for (int ni = 0; ni < 4; ++ni) {
                const float v = acc[mi][ni][r];
                const int col = wc * 64 + ni * 16 + l15;
                if (v > lm) { lm = v; li = col; }           // ascending col per lane
            }
            #pragma unroll
            for (int mk = 8; mk >= 1; mk >>= 1) {
                const float ov = __shfl_xor(lm, mk);
                const int   oi = __shfl_xor(li, mk);
                if (ov > lm || (ov == lm && oi < li)) { lm = ov; li = oi; }
            }
            float le = 0.f;
            #pragma unroll
            for (int ni = 0; ni < 4; ++ni) le += __expf(acc[mi][ni][r] - lm);
            #pragma unroll
            for (int mk = 8; mk >= 1; mk >>= 1) le += __shfl_xor(le, mk);

            if (l15 == 0) { redM[wc][rl] = lm; redS[wc][rl] = le; redI[wc][rl] = li; }

            const int mg = m0 + rl;
            if (mg < MROWS) {
                const int bb = mg / 511, tt = mg - bb * 511;
                const int tv = codes[bb * NPOS + tt + 1];
                const int rel = tv - n0 - wc * 64;
                #pragma unroll
                for (int ni = 0; ni < 4; ++ni) {
                    if (rel >= ni * 16 && rel < ni * 16 + 16 && (rel & 15) == l15)
                        tgtlog[mg] = acc[mi][ni][r];
                }
            }
        }
    }
    __syncthreads();
    if (tid < 128) {
        const int rl = tid;
        const int mg = m0 + rl;
        if (mg < MROWS) {
            const float mA = redM[0][rl], mB = redM[1][rl];
            const int   iA = redI[0][rl], iB = redI[1][rl];
            float gm; int gi;
            if (mB > mA || (mB == mA && iB + 64 < iA)) { gm = mB; gi = 64 + iB; } else { gm = mA; gi = iA; }
            const float S = redS[0][rl] * __expf(mA - gm) + redS[1][rl] * __expf(mB - gm);
            pm[(size_t)vt * MPAD + mg]   = gm;
            ps[(size_t)vt * MPAD + mg]   = S;
            pidx[(size_t)vt * MPAD + mg] = n0 + gi;
        }
    }
}

// ---------------- Kernel 3: combine tile partials per row (NO atomics) ----------------
__global__ __launch_bounds__(256) void combine_kernel(
    const float* __restrict__ pm, const float* __restrict__ ps,
    const int* __restrict__ pidx, const float* __restrict__ tgtlog,
    const int* __restrict__ codes, const int* __restrict__ lens,
    float* __restrict__ rnll, float* __restrict__ rcorr, float* __restrict__ rmf,
    int* __restrict__ presence)
{
    const int g = blockIdx.x * 256 + threadIdx.x;
    if (g >= MROWS) return;
    float gm = -INFINITY; int gi = 0;
    #pragma unroll 8
    for (int nt = 0; nt < NVT; ++nt) {
        const float v = pm[(size_t)nt * MPAD + g];
        if (v > gm) { gm = v; gi = pidx[(size_t)nt * MPAD + g]; }
    }
    float S = 0.f;
    #pragma unroll 8
    for (int nt = 0; nt < NVT; ++nt) S += ps[(size_t)nt * MPAD + g] * __expf(pm[(size_t)nt * MPAD + g] - gm);
    const float lse = gm + logf(S);
    const int b = g / 511, t = g - b * 511;
    const int tv = codes[b * NPOS + t + 1];
    const float nll = lse - tgtlog[g];
    const int L = lens[b];
    const int s = t + 1;
    const bool mf = (s < (L / 4)) && (4 * s + 3 < L);
    rnll[g]  = mf ? nll : 0.f;
    rcorr[g] = (mf && gi == tv) ? 1.f : 0.f;
    rmf[g]   = mf ? 1.f : 0.f;
    if (mf) presence[tv] = 1;   // idempotent plain store; visibility via kernel boundary
}

// ---------------- Kernel 4: final reduction -> 4 scalars ----------------
__global__ __launch_bounds__(256) void finalize_kernel(
    const float* __restrict__ rnll, const float* __restrict__ rcorr,
    const float* __restrict__ rmf, const int* __restrict__ presence,
    float* __restrict__ out)
{
    __shared__ float sh0[256], sh1[256], sh2[256];
    __shared__ int shp[256];
    const int tid = threadIdx.x;
    float sn = 0.f, sc = 0.f, sm = 0.f; int pp = 0;
    for (int g = tid; g < MROWS; g += 256) { sn += rnll[g]; sc += rcorr[g]; sm += rmf[g]; }
    for (int v = tid; v < NEMB; v += 256) pp += presence[v];
    sh0[tid] = sn; sh1[tid] = sc; sh2[tid] = sm; shp[tid] = pp;
    __syncthreads();
    for (int s = 128; s > 0; s >>= 1) {
        if (tid < s) { sh0[tid] += sh0[tid + s]; sh1[tid] += sh1[tid + s]; sh2[tid] += sh2[tid + s]; shp[tid] += shp[tid + s]; }
        __syncthreads();
    }
    if (tid == 0) {
        const float Sm = sh2[0];
        out[0] = sh0[0] / Sm;
        out[1] = sh1[0] / Sm;
        out[2] = Sm;
        out[3] = (float)shp[0];
    }
}

extern "C" void kernel_launch(void* const* d_in, const int* in_sizes, int n_in,
                              void* d_out, int out_size, void* d_ws, size_t ws_size,
                              hipStream_t stream) {
    const float* feats = (const float*)d_in[0];
    const int*   lens  = (const int*)d_in[1];
    const float* enc   = (const float*)d_in[2];
    const float* proj  = (const float*)d_in[3];
    const float* emb   = (const float*)d_in[4];
    const float* tno   = (const float*)d_in[5];
    float* out = (float*)d_out;

    int* codes          = (int*)d_ws;                        // 8192
    int* presence       = codes + MPAD;                      // 8192
    float* pm           = (float*)(presence + MPAD);         // 64*8192
    float* ps           = pm + (size_t)NVT * MPAD;           // 64*8192
    int* pidx           = (int*)(ps + (size_t)NVT * MPAD);   // 64*8192
    float* tgtlog       = (float*)(pidx + (size_t)NVT * MPAD); // 8192
    float* rnll         = tgtlog + MPAD;
    float* rcorr        = rnll + MPAD;
    float* rmf          = rcorr + MPAD;
    unsigned short* encB = (unsigned short*)(rmf + MPAD);    // 8192*512
    unsigned short* tnoT = encB + (size_t)MPAD * ENCD;       // 8192*512

    hipLaunchKernelGGL(prep_kernel, dim3(2048), dim3(256), 0, stream,
                       feats, proj, emb, enc, tno, codes, presence, encB, tnoT);
    hipLaunchKernelGGL(logits_mfma, dim3(64 * 64), dim3(256), 0, stream, encB, tnoT, codes, pm, ps, pidx, tgtlog);
    hipLaunchKernelGGL(combine_kernel, dim3((MROWS + 255) / 256), dim3(256), 0, stream,
                       pm, ps, pidx, tgtlog, codes, lens, rnll, rcorr, rmf, presence);
    hipLaunchKernelGGL(finalize_kernel, dim3(1), dim3(256), 0, stream, rnll, rcorr, rmf, presence, out);
}

// Round 12
// 288.052 us; speedup vs baseline: 1.0142x; 1.0142x over previous
//
#include <hip/hip_runtime.h>
#include <math.h>

typedef __attribute__((ext_vector_type(4))) float f32x4;
typedef __attribute__((ext_vector_type(8))) short bf16x8;

// Problem constants
#define NB 16
#define NT 2048
#define NMEL 80
#define NPOS 512          // stacked positions per batch
#define EDIM 16
#define NEMB 8192
#define ENCD 512
#define MROWS (NB*511)    // 8176 logit rows
#define MPAD 8192
#define NVT 64            // 8192 / 128 col tiles

__device__ __forceinline__ unsigned short f2bf(float x) {
    union { float f; unsigned u; } v; v.f = x;
    unsigned r = v.u + 0x7fffu + ((v.u >> 16) & 1u);
    return (unsigned short)(r >> 16);
}

__device__ __forceinline__ void gl_lds16(const void* gsrc, void* lds) {
    __builtin_amdgcn_global_load_lds(
        (const __attribute__((address_space(1))) unsigned int*)gsrc,
        (__attribute__((address_space(3))) unsigned int*)lds,
        16, 0, 0);
}

// ---------------- Kernel 1: prep = codes (blocks 0..255, 8 pos/wave global scan)
//                  + enc->bf16 (256..767) + tno->bf16 transpose (768..1791).
__global__ __launch_bounds__(256) void prep_kernel(
    const float* __restrict__ feats, const float* __restrict__ proj,
    const float* __restrict__ emb, const float* __restrict__ enc,
    const float* __restrict__ tno,
    int* __restrict__ codes, int* __restrict__ presence,
    unsigned short* __restrict__ encB, unsigned short* __restrict__ tnoT)
{
    __shared__ float tileT[32][33];         // tno transpose staging
    const int bid = blockIdx.x;
    const int tid = threadIdx.x;

    if (bid < 256) {
        // ---- codes path: 8 positions per wave; per-lane global emb scan ----
        const int lane = tid & 63;
        const int wave = tid >> 6;
        const int gbase = bid * 32 + wave * 8;
        if (bid < 32) presence[bid * 256 + tid] = 0;

        float yn[8][EDIM];
        #pragma unroll
        for (int pi = 0; pi < 8; ++pi) {
            const int g = gbase + pi;
            const int b = g >> 9;
            const int i = g & 511;
            float xv[5];
            float s = 0.f, sq = 0.f;
            #pragma unroll
            for (int qq = 0; qq < 5; ++qq) {
                const int d = lane + 64 * qq;
                const int j = d / 80, k = d - j * 80;
                const float v = feats[((b * NT) + (i * 4 + j)) * NMEL + k];
                xv[qq] = v; s += v; sq += v * v;
            }
            for (int m = 1; m < 64; m <<= 1) { s += __shfl_xor(s, m); sq += __shfl_xor(sq, m); }
            const float mean = s * (1.0f / 320.0f);
            const float var  = sq * (1.0f / 320.0f) - mean * mean;
            const float rstd = rsqrtf(var + 1e-6f);
            float acc[EDIM];
            #pragma unroll
            for (int e = 0; e < EDIM; ++e) acc[e] = 0.f;
            #pragma unroll
            for (int qq = 0; qq < 5; ++qq) {
                const int d = lane + 64 * qq;
                const float xn = (xv[qq] - mean) * rstd;
                #pragma unroll
                for (int e = 0; e < EDIM; ++e) acc[e] += xn * proj[d * EDIM + e];
            }
            for (int m = 1; m < 64; m <<= 1) {
                #pragma unroll
                for (int e = 0; e < EDIM; ++e) acc[e] += __shfl_xor(acc[e], m);
            }
            float nsq = 0.f;
            #pragma unroll
            for (int e = 0; e < EDIM; ++e) nsq += acc[e] * acc[e];
            const float inv = 1.0f / (sqrtf(nsq) + 1e-8f);
            #pragma unroll
            for (int e = 0; e < EDIM; ++e) yn[pi][e] = acc[e] * inv;
        }

        // per-lane scan: lane owns embeddings {i*64 + lane}, ascending index
        float mind[8]; int mini[8];
        #pragma unroll
        for (int pi = 0; pi < 8; ++pi) { mind[pi] = INFINITY; mini[pi] = 0x7fffffff; }

        #pragma unroll 2
        for (int i = 0; i < 128; ++i) {
            const int v = i * 64 + lane;
            const float* ep = &emb[(size_t)v * EDIM];
            const float4 e0 = *(const float4*)&ep[0];
            const float4 e1 = *(const float4*)&ep[4];
            const float4 e2v = *(const float4*)&ep[8];
            const float4 e3 = *(const float4*)&ep[12];
            const float e2 = e0.x*e0.x + e0.y*e0.y + e0.z*e0.z + e0.w*e0.w
                           + e1.x*e1.x + e1.y*e1.y + e1.z*e1.z + e1.w*e1.w
                           + e2v.x*e2v.x + e2v.y*e2v.y + e2v.z*e2v.z + e2v.w*e2v.w
                           + e3.x*e3.x + e3.y*e3.y + e3.z*e3.z + e3.w*e3.w;
            const float h2 = 0.5f * e2;
            #pragma unroll
            for (int pi = 0; pi < 8; ++pi) {
                const float dot = yn[pi][0]*e0.x + yn[pi][1]*e0.y + yn[pi][2]*e0.z + yn[pi][3]*e0.w
                                + yn[pi][4]*e1.x + yn[pi][5]*e1.y + yn[pi][6]*e1.z + yn[pi][7]*e1.w
                                + yn[pi][8]*e2v.x + yn[pi][9]*e2v.y + yn[pi][10]*e2v.z + yn[pi][11]*e2v.w
                                + yn[pi][12]*e3.x + yn[pi][13]*e3.y + yn[pi][14]*e3.z + yn[pi][15]*e3.w;
                const float sc = h2 - dot;
                if (sc < mind[pi]) { mind[pi] = sc; mini[pi] = v; }
            }
        }
        for (int m = 1; m < 64; m <<= 1) {
            #pragma unroll
            for (int pi = 0; pi < 8; ++pi) {
                const float ov = __shfl_xor(mind[pi], m);
                const int   oi = __shfl_xor(mini[pi], m);
                if (ov < mind[pi] || (ov == mind[pi] && oi < mini[pi])) { mind[pi] = ov; mini[pi] = oi; }
            }
        }
        if (lane == 0) {
            #pragma unroll
            for (int pi = 0; pi < 8; ++pi) codes[gbase + pi] = mini[pi];
        }
    } else if (bid < 768) {
        // ---- enc f32 -> encB bf16 [8192][512], padded rows zero ----
        const int bid2 = bid - 256;          // 0..511 -> 16 rows each
        #pragma unroll
        for (int pass = 0; pass < 4; ++pass) {
            const int m = bid2 * 16 + pass * 4 + (tid >> 6);
            const int d = (tid & 63) * 8;
            bf16x8 o;
            if (m < MROWS) {
                const int b = m / 511, t = m - b * 511;
                const float4 f0 = *(const float4*)&enc[((size_t)(b * 512 + t)) * ENCD + d];
                const float4 f1 = *(const float4*)&enc[((size_t)(b * 512 + t)) * ENCD + d + 4];
                o[0] = f2bf(f0.x); o[1] = f2bf(f0.y); o[2] = f2bf(f0.z); o[3] = f2bf(f0.w);
                o[4] = f2bf(f1.x); o[5] = f2bf(f1.y); o[6] = f2bf(f1.z); o[7] = f2bf(f1.w);
            } else {
                o = (bf16x8){0,0,0,0,0,0,0,0};
            }
            *(bf16x8*)&encB[(size_t)m * ENCD + d] = o;
        }
    } else {
        // ---- tno f32 [512][8192] -> tnoT bf16 [8192][512] ----
        const int bid2 = bid - 768;          // 0..1023 -> 4 tiles each
        const int tx = tid & 31, ty = tid >> 5;   // 32 x 8
        #pragma unroll
        for (int it = 0; it < 4; ++it) {
            const int tile = bid2 * 4 + it;       // 0..4095
            const int n0 = (tile & 255) * 32;
            const int k0 = (tile >> 8) * 32;
            __syncthreads();
            #pragma unroll
            for (int i = 0; i < 4; ++i)
                tileT[ty + 8 * i][tx] = tno[(size_t)(k0 + ty + 8 * i) * NEMB + n0 + tx];
            __syncthreads();
            #pragma unroll
            for (int i = 0; i < 4; ++i)
                tnoT[(size_t)(n0 + ty + 8 * i) * ENCD + k0 + tx] = f2bf(tileT[tx][ty + 8 * i]);
        }
    }
}

// ---------------- Kernel 2: bf16 MFMA GEMM, BK=32, triple-buffered counted-vmcnt (r4-proven) ----
__global__ __launch_bounds__(256, 3) void logits_mfma(
    const unsigned short* __restrict__ encB, const unsigned short* __restrict__ tnoT,
    const int* __restrict__ codes,
    float* __restrict__ pm, float* __restrict__ ps, int* __restrict__ pidx,
    float* __restrict__ tgtlog)
{
    __shared__ __align__(16) unsigned short As3[3][128 * 32];
    __shared__ __align__(16) unsigned short Bs3[3][128 * 32];
    __shared__ float redM[2][128];
    __shared__ float redS[2][128];
    __shared__ int   redI[2][128];

    const int tid  = threadIdx.x;
    const int lane = tid & 63;
    const int wave = tid >> 6;
    const int wr = wave >> 1, wc = wave & 1;

    // XCD-aware mapping, mt-fastest within each XCD chunk
    const int bid = blockIdx.x;
    const int xcd = bid & 7;
    const int idx = bid >> 3;
    const int mt  = xcd * 8 + (idx & 7);
    const int vt  = idx >> 3;
    const int m0 = mt * 128, n0 = vt * 128;

    // staging lane constants: rows of 32 bf16 (64B); involution slot = chunk ^ ((r>>1)&3)
    const int rb  = lane >> 2;                               // 0..15
    const int gc8 = ((lane & 3) ^ ((lane >> 3) & 3)) * 8;    // pre-swizzled source chunk
    const size_t abase0 = (size_t)(m0 + wave * 32 + rb) * ENCD + gc8;
    const size_t bbase0 = (size_t)(n0 + wave * 32 + rb) * ENCD + gc8;

#define STAGE(t, buf)                                                                        \
    {                                                                                        \
        const int k0s = (t) * 32;                                                            \
        gl_lds16(encB + abase0 + k0s,              &As3[buf][(wave * 32) * 32]);             \
        gl_lds16(tnoT + bbase0 + k0s,              &Bs3[buf][(wave * 32) * 32]);             \
        gl_lds16(encB + abase0 + 16 * ENCD + k0s,  &As3[buf][(wave * 32 + 16) * 32]);        \
        gl_lds16(tnoT + bbase0 + 16 * ENCD + k0s,  &Bs3[buf][(wave * 32 + 16) * 32]);        \
    }

    f32x4 acc[4][4];
    #pragma unroll
    for (int i = 0; i < 4; ++i)
        #pragma unroll
        for (int j = 0; j < 4; ++j)
            acc[i][j] = (f32x4){0.f, 0.f, 0.f, 0.f};

    const int l15 = lane & 15, q = lane >> 4;
    const int ca = (q ^ ((l15 >> 1) & 3)) * 8;   // swizzled chunk offset for fragment reads

    STAGE(0, 0);
    STAGE(1, 1);

    #pragma unroll
    for (int t = 0; t < 16; ++t) {
        if (t < 15) { asm volatile("s_waitcnt vmcnt(4)" ::: "memory"); }
        else        { asm volatile("s_waitcnt vmcnt(0)" ::: "memory"); }
        __builtin_amdgcn_s_barrier();
        __builtin_amdgcn_sched_barrier(0);
        if (t + 2 < 16) {
            const int nb = (t + 2) % 3;
            STAGE(t + 2, nb);
        }
        const unsigned short* Ab = As3[t % 3];
        const unsigned short* Bb = Bs3[t % 3];
        bf16x8 a[4], b[4];
        #pragma unroll
        for (int mi = 0; mi < 4; ++mi)
            a[mi] = *(const bf16x8*)&Ab[(wr * 64 + mi * 16 + l15) * 32 + ca];
        #pragma unroll
        for (int ni = 0; ni < 4; ++ni)
            b[ni] = *(const bf16x8*)&Bb[(wc * 64 + ni * 16 + l15) * 32 + ca];
        __builtin_amdgcn_s_setprio(1);
        #pragma unroll
        for (int mi = 0; mi < 4; ++mi)
            #pragma unroll
            for (int ni = 0; ni < 4; ++ni)
                acc[mi][ni] = __builtin_amdgcn_mfma_f32_16x16x32_bf16(a[mi], b[ni], acc[mi][ni], 0, 0, 0);
        __builtin_amdgcn_s_setprio(0);
    }
#undef STAGE

    // Epilogue: per-row partial max / first-argmax / sumexp over this block's 128 cols.
    #pragma unroll
    for (int mi = 0; mi < 4; ++mi) {
        #pragma unroll
        for (int r = 0; r < 4; ++r) {
            const int rl = wr * 64 + mi * 16 + q * 4 + r;   // local row 0..127
            float lm = -INFINITY; int li = 0;
            #pragma unroll
            for (int ni = 0; ni < 4; ++ni) {
                const float v = acc[mi][ni][r];
                const int col = wc * 64 + ni * 16 + l15;
                if (v > lm) { lm = v; li = col; }           // ascending col per lane
            }
            #pragma unroll
            for (int mk = 8; mk >= 1; mk >>= 1) {
                const float ov = __shfl_xor(lm, mk);
                const int   oi = __shfl_xor(li, mk);
                if (ov > lm || (ov == lm && oi < li)) { lm = ov; li = oi; }
            }
            float le = 0.f;
            #pragma unroll
            for (int ni = 0; ni < 4; ++ni) le += __expf(acc[mi][ni][r] - lm);
            #pragma unroll
            for (int mk = 8; mk >= 1; mk >>= 1) le += __shfl_xor(le, mk);

            if (l15 == 0) { redM[wc][rl] = lm; redS[wc][rl] = le; redI[wc][rl] = li; }

            const int mg = m0 + rl;
            if (mg < MROWS) {
                const int bb = mg / 511, tt = mg - bb * 511;
                const int tv = codes[bb * NPOS + tt + 1];
                const int rel = tv - n0 - wc * 64;
                #pragma unroll
                for (int ni = 0; ni < 4; ++ni) {
                    if (rel >= ni * 16 && rel < ni * 16 + 16 && (rel & 15) == l15)
                        tgtlog[mg] = acc[mi][ni][r];
                }
            }
        }
    }
    __syncthreads();
    if (tid < 128) {
        const int rl = tid;
        const int mg = m0 + rl;
        if (mg < MROWS) {
            const float mA = redM[0][rl], mB = redM[1][rl];
            const int   iA = redI[0][rl], iB = redI[1][rl];
            float gm; int gi;
            if (mB > mA || (mB == mA && iB + 64 < iA)) { gm = mB; gi = 64 + iB; } else { gm = mA; gi = iA; }
            const float S = redS[0][rl] * __expf(mA - gm) + redS[1][rl] * __expf(mB - gm);
            pm[(size_t)vt * MPAD + mg]   = gm;
            ps[(size_t)vt * MPAD + mg]   = S;
            pidx[(size_t)vt * MPAD + mg] = n0 + gi;
        }
    }
}

// ---------------- Kernel 3: combine tile partials per row (NO atomics) ----------------
__global__ __launch_bounds__(256) void combine_kernel(
    const float* __restrict__ pm, const float* __restrict__ ps,
    const int* __restrict__ pidx, const float* __restrict__ tgtlog,
    const int* __restrict__ codes, const int* __restrict__ lens,
    float* __restrict__ rnll, float* __restrict__ rcorr, float* __restrict__ rmf,
    int* __restrict__ presence)
{
    const int g = blockIdx.x * 256 + threadIdx.x;
    if (g >= MROWS) return;
    float gm = -INFINITY; int gi = 0;
    #pragma unroll 8
    for (int nt = 0; nt < NVT; ++nt) {
        const float v = pm[(size_t)nt * MPAD + g];
        if (v > gm) { gm = v; gi = pidx[(size_t)nt * MPAD + g]; }
    }
    float S = 0.f;
    #pragma unroll 8
    for (int nt = 0; nt < NVT; ++nt) S += ps[(size_t)nt * MPAD + g] * __expf(pm[(size_t)nt * MPAD + g] - gm);
    const float lse = gm + logf(S);
    const int b = g / 511, t = g - b * 511;
    const int tv = codes[b * NPOS + t + 1];
    const float nll = lse - tgtlog[g];
    const int L = lens[b];
    const int s = t + 1;
    const bool mf = (s < (L / 4)) && (4 * s + 3 < L);
    rnll[g]  = mf ? nll : 0.f;
    rcorr[g] = (mf && gi == tv) ? 1.f : 0.f;
    rmf[g]   = mf ? 1.f : 0.f;
    if (mf) presence[tv] = 1;   // idempotent plain store; visibility via kernel boundary
}

// ---------------- Kernel 4: final reduction -> 4 scalars ----------------
__global__ __launch_bounds__(256) void finalize_kernel(
    const float* __restrict__ rnll, const float* __restrict__ rcorr,
    const float* __restrict__ rmf, const int* __restrict__ presence,
    float* __restrict__ out)
{
    __shared__ float sh0[256], sh1[256], sh2[256];
    __shared__ int shp[256];
    const int tid = threadIdx.x;
    float sn = 0.f, sc = 0.f, sm = 0.f; int pp = 0;
    for (int g = tid; g < MROWS; g += 256) { sn += rnll[g]; sc += rcorr[g]; sm += rmf[g]; }
    for (int v = tid; v < NEMB; v += 256) pp += presence[v];
    sh0[tid] = sn; sh1[tid] = sc; sh2[tid] = sm; shp[tid] = pp;
    __syncthreads();
    for (int s = 128; s > 0; s >>= 1) {
        if (tid < s) { sh0[tid] += sh0[tid + s]; sh1[tid] += sh1[tid + s]; sh2[tid] += sh2[tid + s]; shp[tid] += shp[tid + s]; }
        __syncthreads();
    }
    if (tid == 0) {
        const float Sm = sh2[0];
        out[0] = sh0[0] / Sm;
        out[1] = sh1[0] / Sm;
        out[2] = Sm;
        out[3] = (float)shp[0];
    }
}

extern "C" void kernel_launch(void* const* d_in, const int* in_sizes, int n_in,
                              void* d_out, int out_size, void* d_ws, size_t ws_size,
                              hipStream_t stream) {
    const float* feats = (const float*)d_in[0];
    const int*   lens  = (const int*)d_in[1];
    const float* enc   = (const float*)d_in[2];
    const float* proj  = (const float*)d_in[3];
    const float* emb   = (const float*)d_in[4];
    const float* tno   = (const float*)d_in[5];
    float* out = (float*)d_out;

    int* codes          = (int*)d_ws;                        // 8192
    int* presence       = codes + MPAD;                      // 8192
    float* pm           = (float*)(presence + MPAD);         // 64*8192
    float* ps           = pm + (size_t)NVT * MPAD;           // 64*8192
    int* pidx           = (int*)(ps + (size_t)NVT * MPAD);   // 64*8192
    float* tgtlog       = (float*)(pidx + (size_t)NVT * MPAD); // 8192
    float* rnll         = tgtlog + MPAD;
    float* rcorr        = rnll + MPAD;
    float* rmf          = rcorr + MPAD;
    unsigned short* encB = (unsigned short*)(rmf + MPAD);    // 8192*512
    unsigned short* tnoT = encB + (size_t)MPAD * ENCD;       // 8192*512

    hipLaunchKernelGGL(prep_kernel, dim3(1792), dim3(256), 0, stream,
                       feats, proj, emb, enc, tno, codes, presence, encB, tnoT);
    hipLaunchKernelGGL(logits_mfma, dim3(64 * 64), dim3(256), 0, stream, encB, tnoT, codes, pm, ps, pidx, tgtlog);
    hipLaunchKernelGGL(combine_kernel, dim3((MROWS + 255) / 256), dim3(256), 0, stream,
                       pm, ps, pidx, tgtlog, codes, lens, rnll, rcorr, rmf, presence);
    hipLaunchKernelGGL(finalize_kernel, dim3(1), dim3(256), 0, stream, rnll, rcorr, rmf, presence, out);
}

// Round 13
// 245.175 us; speedup vs baseline: 1.1915x; 1.1749x over previous
//
#include <hip/hip_runtime.h>
#include <math.h>

typedef __attribute__((ext_vector_type(4))) float f32x4;
typedef __attribute__((ext_vector_type(8))) short bf16x8;

// Problem constants
#define NB 16
#define NT 2048
#define NMEL 80
#define NPOS 512          // stacked positions per batch
#define EDIM 16
#define NEMB 8192
#define ENCD 512
#define MROWS (NB*511)    // 8176 logit rows
#define MPAD 8192
#define NVT 64            // 8192 / 128 col tiles

__device__ __forceinline__ void gl_lds16(const void* gsrc, void* lds) {
    __builtin_amdgcn_global_load_lds(
        (const __attribute__((address_space(1))) unsigned int*)gsrc,
        (__attribute__((address_space(3))) unsigned int*)lds,
        16, 0, 0);
}

// ---------------- Kernel 1: prep = codes (blocks 0..511, 4 pos/wave global scan)
//                  + enc->fp8 (512..1023) + tno->fp8 transpose x16 (1024..2047).
__global__ __launch_bounds__(256) void prep_kernel(
    const float* __restrict__ feats, const float* __restrict__ proj,
    const float* __restrict__ emb, const float* __restrict__ enc,
    const float* __restrict__ tno,
    int* __restrict__ codes, int* __restrict__ presence,
    unsigned char* __restrict__ encF8, unsigned char* __restrict__ tnoF8)
{
    __shared__ float tileT[32][33];         // tno transpose staging
    const int bid = blockIdx.x;
    const int tid = threadIdx.x;

    if (bid < 512) {
        // ---- codes path: per-lane global emb scan (r11-proven) ----
        const int lane = tid & 63;
        const int wave = tid >> 6;
        const int gbase = bid * 16 + wave * 4;
        if (bid < 32) presence[bid * 256 + tid] = 0;

        float yn[4][EDIM];
        #pragma unroll
        for (int pi = 0; pi < 4; ++pi) {
            const int g = gbase + pi;
            const int b = g >> 9;
            const int i = g & 511;
            float xv[5];
            float s = 0.f, sq = 0.f;
            #pragma unroll
            for (int qq = 0; qq < 5; ++qq) {
                const int d = lane + 64 * qq;
                const int j = d / 80, k = d - j * 80;
                const float v = feats[((b * NT) + (i * 4 + j)) * NMEL + k];
                xv[qq] = v; s += v; sq += v * v;
            }
            for (int m = 1; m < 64; m <<= 1) { s += __shfl_xor(s, m); sq += __shfl_xor(sq, m); }
            const float mean = s * (1.0f / 320.0f);
            const float var  = sq * (1.0f / 320.0f) - mean * mean;
            const float rstd = rsqrtf(var + 1e-6f);
            float acc[EDIM];
            #pragma unroll
            for (int e = 0; e < EDIM; ++e) acc[e] = 0.f;
            #pragma unroll
            for (int qq = 0; qq < 5; ++qq) {
                const int d = lane + 64 * qq;
                const float xn = (xv[qq] - mean) * rstd;
                #pragma unroll
                for (int e = 0; e < EDIM; ++e) acc[e] += xn * proj[d * EDIM + e];
            }
            for (int m = 1; m < 64; m <<= 1) {
                #pragma unroll
                for (int e = 0; e < EDIM; ++e) acc[e] += __shfl_xor(acc[e], m);
            }
            float nsq = 0.f;
            #pragma unroll
            for (int e = 0; e < EDIM; ++e) nsq += acc[e] * acc[e];
            const float inv = 1.0f / (sqrtf(nsq) + 1e-8f);
            #pragma unroll
            for (int e = 0; e < EDIM; ++e) yn[pi][e] = acc[e] * inv;
        }

        float mind[4]; int mini[4];
        #pragma unroll
        for (int pi = 0; pi < 4; ++pi) { mind[pi] = INFINITY; mini[pi] = 0x7fffffff; }

        #pragma unroll 2
        for (int i = 0; i < 128; ++i) {
            const int v = i * 64 + lane;
            const float* ep = &emb[(size_t)v * EDIM];
            const float4 e0 = *(const float4*)&ep[0];
            const float4 e1 = *(const float4*)&ep[4];
            const float4 e2v = *(const float4*)&ep[8];
            const float4 e3 = *(const float4*)&ep[12];
            const float e2 = e0.x*e0.x + e0.y*e0.y + e0.z*e0.z + e0.w*e0.w
                           + e1.x*e1.x + e1.y*e1.y + e1.z*e1.z + e1.w*e1.w
                           + e2v.x*e2v.x + e2v.y*e2v.y + e2v.z*e2v.z + e2v.w*e2v.w
                           + e3.x*e3.x + e3.y*e3.y + e3.z*e3.z + e3.w*e3.w;
            const float h2 = 0.5f * e2;
            #pragma unroll
            for (int pi = 0; pi < 4; ++pi) {
                const float dot = yn[pi][0]*e0.x + yn[pi][1]*e0.y + yn[pi][2]*e0.z + yn[pi][3]*e0.w
                                + yn[pi][4]*e1.x + yn[pi][5]*e1.y + yn[pi][6]*e1.z + yn[pi][7]*e1.w
                                + yn[pi][8]*e2v.x + yn[pi][9]*e2v.y + yn[pi][10]*e2v.z + yn[pi][11]*e2v.w
                                + yn[pi][12]*e3.x + yn[pi][13]*e3.y + yn[pi][14]*e3.z + yn[pi][15]*e3.w;
                const float sc = h2 - dot;
                if (sc < mind[pi]) { mind[pi] = sc; mini[pi] = v; }
            }
        }
        for (int m = 1; m < 64; m <<= 1) {
            #pragma unroll
            for (int pi = 0; pi < 4; ++pi) {
                const float ov = __shfl_xor(mind[pi], m);
                const int   oi = __shfl_xor(mini[pi], m);
                if (ov < mind[pi] || (ov == mind[pi] && oi < mini[pi])) { mind[pi] = ov; mini[pi] = oi; }
            }
        }
        if (lane == 0) {
            #pragma unroll
            for (int pi = 0; pi < 4; ++pi) codes[gbase + pi] = mini[pi];
        }
    } else if (bid < 1024) {
        // ---- enc f32 -> encF8 e4m3 [8192][512] bytes, padded rows zero ----
        const int bid2 = bid - 512;          // 0..511 -> 16 rows each
        const int lane = tid & 63;
        #pragma unroll
        for (int pass = 0; pass < 4; ++pass) {
            const int m = bid2 * 16 + pass * 4 + (tid >> 6);
            const int d = lane * 8;
            uint2 o = make_uint2(0u, 0u);
            if (m < MROWS) {
                const int b = m / 511, t = m - b * 511;
                const float4 f0 = *(const float4*)&enc[((size_t)(b * 512 + t)) * ENCD + d];
                const float4 f1 = *(const float4*)&enc[((size_t)(b * 512 + t)) * ENCD + d + 4];
                int w0 = __builtin_amdgcn_cvt_pk_fp8_f32(f0.x, f0.y, 0, false);
                w0     = __builtin_amdgcn_cvt_pk_fp8_f32(f0.z, f0.w, w0, true);
                int w1 = __builtin_amdgcn_cvt_pk_fp8_f32(f1.x, f1.y, 0, false);
                w1     = __builtin_amdgcn_cvt_pk_fp8_f32(f1.z, f1.w, w1, true);
                o.x = (unsigned)w0; o.y = (unsigned)w1;
            }
            *(uint2*)&encF8[(size_t)m * ENCD + d] = o;
        }
    } else {
        // ---- tno f32 [512][8192] -> tnoF8 e4m3 [8192][512] bytes, scaled x16 ----
        const int bid2 = bid - 1024;         // 0..1023 -> 4 tiles each
        const int tx = tid & 31, ty = tid >> 5;   // 32 x 8 loaders
        const int np = tid >> 3, kc = tid & 7;    // 32 n-rows x 8 k-quads writers
        #pragma unroll
        for (int it = 0; it < 4; ++it) {
            const int tile = bid2 * 4 + it;       // 0..4095
            const int n0 = (tile & 255) * 32;
            const int k0 = (tile >> 8) * 32;
            __syncthreads();
            #pragma unroll
            for (int i = 0; i < 4; ++i)
                tileT[ty + 8 * i][tx] = tno[(size_t)(k0 + ty + 8 * i) * NEMB + n0 + tx];
            __syncthreads();
            const float t0 = 16.0f * tileT[kc * 4 + 0][np];
            const float t1 = 16.0f * tileT[kc * 4 + 1][np];
            const float t2 = 16.0f * tileT[kc * 4 + 2][np];
            const float t3 = 16.0f * tileT[kc * 4 + 3][np];
            int w = __builtin_amdgcn_cvt_pk_fp8_f32(t0, t1, 0, false);
            w     = __builtin_amdgcn_cvt_pk_fp8_f32(t2, t3, w, true);
            ((unsigned*)tnoF8)[(size_t)(n0 + np) * (ENCD / 4) + (k0 >> 2) + kc] = (unsigned)w;
        }
    }
}

// ---------------- Kernel 2: fp8 MFMA GEMM, BK=64, triple-buffered counted-vmcnt
//                  (r4 schedule byte-for-byte; fp8 halves LDS bytes per MFMA) ----
__global__ __launch_bounds__(256, 3) void logits_mfma(
    const unsigned char* __restrict__ encF8, const unsigned char* __restrict__ tnoF8,
    const int* __restrict__ codes,
    float* __restrict__ pm, float* __restrict__ ps, int* __restrict__ pidx,
    float* __restrict__ tgtlog)
{
    __shared__ __align__(16) unsigned char As3[3][128 * 64];   // 24 KB
    __shared__ __align__(16) unsigned char Bs3[3][128 * 64];   // 24 KB
    __shared__ float redM[2][128];
    __shared__ float redS[2][128];
    __shared__ int   redI[2][128];

    const int tid  = threadIdx.x;
    const int lane = tid & 63;
    const int wave = tid >> 6;
    const int wr = wave >> 1, wc = wave & 1;

    // XCD-aware mapping, mt-fastest within each XCD chunk
    const int bid = blockIdx.x;
    const int xcd = bid & 7;
    const int idx = bid >> 3;
    const int mt  = xcd * 8 + (idx & 7);
    const int vt  = idx >> 3;
    const int m0 = mt * 128, n0 = vt * 128;

    // staging: rows of 64 fp8 (64B, 4 chunks of 16B); involution slot = chunk ^ ((r>>1)&3)
    const int rb   = lane >> 2;                                // 0..15
    const int gcB  = ((lane & 3) ^ ((lane >> 3) & 3)) * 16;    // pre-swizzled source chunk (bytes)
    const size_t abase0 = (size_t)(m0 + wave * 32 + rb) * ENCD + gcB;
    const size_t bbase0 = (size_t)(n0 + wave * 32 + rb) * ENCD + gcB;

#define STAGE(t, buf)                                                                        \
    {                                                                                        \
        const int k0s = (t) * 64;                                                            \
        gl_lds16(encF8 + abase0 + k0s,              &As3[buf][(wave * 32) * 64]);            \
        gl_lds16(tnoF8 + bbase0 + k0s,              &Bs3[buf][(wave * 32) * 64]);            \
        gl_lds16(encF8 + abase0 + 16 * ENCD + k0s,  &As3[buf][(wave * 32 + 16) * 64]);       \
        gl_lds16(tnoF8 + bbase0 + 16 * ENCD + k0s,  &Bs3[buf][(wave * 32 + 16) * 64]);       \
    }

    f32x4 acc[4][4];
    #pragma unroll
    for (int i = 0; i < 4; ++i)
        #pragma unroll
        for (int j = 0; j < 4; ++j)
            acc[i][j] = (f32x4){0.f, 0.f, 0.f, 0.f};

    const int l15 = lane & 15, q = lane >> 4;
    const int rsw = (l15 >> 1) & 3;   // row part of read swizzle

    STAGE(0, 0);
    STAGE(1, 1);

    #pragma unroll
    for (int t = 0; t < 8; ++t) {
        if (t < 7) { asm volatile("s_waitcnt vmcnt(4)" ::: "memory"); }
        else       { asm volatile("s_waitcnt vmcnt(0)" ::: "memory"); }
        __builtin_amdgcn_s_barrier();
        __builtin_amdgcn_sched_barrier(0);
        if (t + 2 < 8) {
            const int nb = (t + 2) % 3;
            STAGE(t + 2, nb);
        }
        const unsigned char* Ab = As3[t % 3];
        const unsigned char* Bb = Bs3[t % 3];
        #pragma unroll
        for (int ks = 0; ks < 2; ++ks) {
            // lane needs bytes [ks*32 + q*8 .. +8) of its 64B row; chunk = ks*2+(q>>1)
            const int co = ((ks * 2 + (q >> 1)) ^ rsw) * 16 + (q & 1) * 8;
            long a[4], b[4];
            #pragma unroll
            for (int mi = 0; mi < 4; ++mi)
                a[mi] = *(const long*)&Ab[(wr * 64 + mi * 16 + l15) * 64 + co];
            #pragma unroll
            for (int ni = 0; ni < 4; ++ni)
                b[ni] = *(const long*)&Bb[(wc * 64 + ni * 16 + l15) * 64 + co];
            __builtin_amdgcn_s_setprio(1);
            #pragma unroll
            for (int mi = 0; mi < 4; ++mi)
                #pragma unroll
                for (int ni = 0; ni < 4; ++ni)
                    acc[mi][ni] = __builtin_amdgcn_mfma_f32_16x16x32_fp8_fp8(a[mi], b[ni], acc[mi][ni], 0, 0, 0);
            __builtin_amdgcn_s_setprio(0);
        }
    }
#undef STAGE

    // undo the tno x16 scaling (exact pow2)
    #pragma unroll
    for (int mi = 0; mi < 4; ++mi)
        #pragma unroll
        for (int ni = 0; ni < 4; ++ni)
            acc[mi][ni] *= 0.0625f;

    // Epilogue: per-row partial max / first-argmax / sumexp over this block's 128 cols.
    #pragma unroll
    for (int mi = 0; mi < 4; ++mi) {
        #pragma unroll
        for (int r = 0; r < 4; ++r) {
            const int rl = wr * 64 + mi * 16 + q * 4 + r;   // local row 0..127
            float lm = -INFINITY; int li = 0;
            #pragma unroll
            for (int ni = 0; ni < 4; ++ni) {
                const float v = acc[mi][ni][r];
                const int col = wc * 64 + ni * 16 + l15;
                if (v > lm) { lm = v; li = col; }           // ascending col per lane
            }
            #pragma unroll
            for (int mk = 8; mk >= 1; mk >>= 1) {
                const float ov = __shfl_xor(lm, mk);
                const int   oi = __shfl_xor(li, mk);
                if (ov > lm || (ov == lm && oi < li)) { lm = ov; li = oi; }
            }
            float le = 0.f;
            #pragma unroll
            for (int ni = 0; ni < 4; ++ni) le += __expf(acc[mi][ni][r] - lm);
            #pragma unroll
            for (int mk = 8; mk >= 1; mk >>= 1) le += __shfl_xor(le, mk);

            if (l15 == 0) { redM[wc][rl] = lm; redS[wc][rl] = le; redI[wc][rl] = li; }

            const int mg = m0 + rl;
            if (mg < MROWS) {
                const int bb = mg / 511, tt = mg - bb * 511;
                const int tv = codes[bb * NPOS + tt + 1];
                const int rel = tv - n0 - wc * 64;
                #pragma unroll
                for (int ni = 0; ni < 4; ++ni) {
                    if (rel >= ni * 16 && rel < ni * 16 + 16 && (rel & 15) == l15)
                        tgtlog[mg] = acc[mi][ni][r];
                }
            }
        }
    }
    __syncthreads();
    if (tid < 128) {
        const int rl = tid;
        const int mg = m0 + rl;
        if (mg < MROWS) {
            const float mA = redM[0][rl], mB = redM[1][rl];
            const int   iA = redI[0][rl], iB = redI[1][rl];
            float gm; int gi;
            if (mB > mA || (mB == mA && iB + 64 < iA)) { gm = mB; gi = 64 + iB; } else { gm = mA; gi = iA; }
            const float S = redS[0][rl] * __expf(mA - gm) + redS[1][rl] * __expf(mB - gm);
            pm[(size_t)vt * MPAD + mg]   = gm;
            ps[(size_t)vt * MPAD + mg]   = S;
            pidx[(size_t)vt * MPAD + mg] = n0 + gi;
        }
    }
}

// ---------------- Kernel 3: combine tile partials per row (NO atomics) ----------------
__global__ __launch_bounds__(256) void combine_kernel(
    const float* __restrict__ pm, const float* __restrict__ ps,
    const int* __restrict__ pidx, const float* __restrict__ tgtlog,
    const int* __restrict__ codes, const int* __restrict__ lens,
    float* __restrict__ rnll, float* __restrict__ rcorr, float* __restrict__ rmf,
    int* __restrict__ presence)
{
    const int g = blockIdx.x * 256 + threadIdx.x;
    if (g >= MROWS) return;
    float gm = -INFINITY; int gi = 0;
    #pragma unroll 8
    for (int nt = 0; nt < NVT; ++nt) {
        const float v = pm[(size_t)nt * MPAD + g];
        if (v > gm) { gm = v; gi = pidx[(size_t)nt * MPAD + g]; }
    }
    float S = 0.f;
    #pragma unroll 8
    for (int nt = 0; nt < NVT; ++nt) S += ps[(size_t)nt * MPAD + g] * __expf(pm[(size_t)nt * MPAD + g] - gm);
    const float lse = gm + logf(S);
    const int b = g / 511, t = g - b * 511;
    const int tv = codes[b * NPOS + t + 1];
    const float nll = lse - tgtlog[g];
    const int L = lens[b];
    const int s = t + 1;
    const bool mf = (s < (L / 4)) && (4 * s + 3 < L);
    rnll[g]  = mf ? nll : 0.f;
    rcorr[g] = (mf && gi == tv) ? 1.f : 0.f;
    rmf[g]   = mf ? 1.f : 0.f;
    if (mf) presence[tv] = 1;   // idempotent plain store; visibility via kernel boundary
}

// ---------------- Kernel 4: final reduction -> 4 scalars ----------------
__global__ __launch_bounds__(256) void finalize_kernel(
    const float* __restrict__ rnll, const float* __restrict__ rcorr,
    const float* __restrict__ rmf, const int* __restrict__ presence,
    float* __restrict__ out)
{
    __shared__ float sh0[256], sh1[256], sh2[256];
    __shared__ int shp[256];
    const int tid = threadIdx.x;
    float sn = 0.f, sc = 0.f, sm = 0.f; int pp = 0;
    for (int g = tid; g < MROWS; g += 256) { sn += rnll[g]; sc += rcorr[g]; sm += rmf[g]; }
    for (int v = tid; v < NEMB; v += 256) pp += presence[v];
    sh0[tid] = sn; sh1[tid] = sc; sh2[tid] = sm; shp[tid] = pp;
    __syncthreads();
    for (int s = 128; s > 0; s >>= 1) {
        if (tid < s) { sh0[tid] += sh0[tid + s]; sh1[tid] += sh1[tid + s]; sh2[tid] += sh2[tid + s]; shp[tid] += shp[tid + s]; }
        __syncthreads();
    }
    if (tid == 0) {
        const float Sm = sh2[0];
        out[0] = sh0[0] / Sm;
        out[1] = sh1[0] / Sm;
        out[2] = Sm;
        out[3] = (float)shp[0];
    }
}

extern "C" void kernel_launch(void* const* d_in, const int* in_sizes, int n_in,
                              void* d_out, int out_size, void* d_ws, size_t ws_size,
                              hipStream_t stream) {
    const float* feats = (const float*)d_in[0];
    const int*   lens  = (const int*)d_in[1];
    const float* enc   = (const float*)d_in[2];
    const float* proj  = (const float*)d_in[3];
    const float* emb   = (const float*)d_in[4];
    const float* tno   = (const float*)d_in[5];
    float* out = (float*)d_out;

    int* codes          = (int*)d_ws;                        // 8192
    int* presence       = codes + MPAD;                      // 8192
    float* pm           = (float*)(presence + MPAD);         // 64*8192
    float* ps           = pm + (size_t)NVT * MPAD;           // 64*8192
    int* pidx           = (int*)(ps + (size_t)NVT * MPAD);   // 64*8192
    float* tgtlog       = (float*)(pidx + (size_t)NVT * MPAD); // 8192
    float* rnll         = tgtlog + MPAD;
    float* rcorr        = rnll + MPAD;
    float* rmf          = rcorr + MPAD;
    unsigned char* encF8 = (unsigned char*)(rmf + MPAD);     // 8192*512 bytes
    unsigned char* tnoF8 = encF8 + (size_t)MPAD * ENCD;      // 8192*512 bytes

    hipLaunchKernelGGL(prep_kernel, dim3(2048), dim3(256), 0, stream,
                       feats, proj, emb, enc, tno, codes, presence, encF8, tnoF8);
    hipLaunchKernelGGL(logits_mfma, dim3(64 * 64), dim3(256), 0, stream, encF8, tnoF8, codes, pm, ps, pidx, tgtlog);
    hipLaunchKernelGGL(combine_kernel, dim3((MROWS + 255) / 256), dim3(256), 0, stream,
                       pm, ps, pidx, tgtlog, codes, lens, rnll, rcorr, rmf, presence);
    hipLaunchKernelGGL(finalize_kernel, dim3(1), dim3(256), 0, stream, rnll, rcorr, rmf, presence, out);
}